// Round 1
// baseline (10898.351 us; speedup 1.0000x reference)
//
#include <hip/hip_runtime.h>
#include <hip/hip_bf16.h>
#include <stdint.h>

#define NT 365
#define NGRID 512
#define NX 256
#define HID 1024
#define KTOT 1280

typedef __bf16 bf16x8 __attribute__((ext_vector_type(8)));
typedef float f32x16 __attribute__((ext_vector_type(16)));

__device__ __forceinline__ unsigned short f2bf(float f) {
    union { float f; uint32_t u; } v; v.f = f;
    uint32_t u = v.u;
    uint32_t r = (u + 0x7FFFu + ((u >> 16) & 1u)) >> 16;
    return (unsigned short)r;
}

__device__ __forceinline__ float sigmoidf_(float x) {
    return 1.0f / (1.0f + __expf(-x));
}

// ---------------- prep kernels ----------------

// Pack [W_hh | W_ih] (fp32, row g, K = 1024 | 256) into bf16 MFMA-B-fragment order.
// Layout: Wpack[gt][kt][lane][8e], gt = g/32 (128 tiles), kt = k/16 (80 tiles).
// B frag (32x32x16): n = lane&31, k = (lane>>5)*8 + e.
__global__ void pack_w_kernel(const float* __restrict__ W_ih,
                              const float* __restrict__ W_hh,
                              unsigned short* __restrict__ Wpack) {
    int tid = blockIdx.x * blockDim.x + threadIdx.x; // one thread per 8-elem group
    if (tid >= 128 * 80 * 64) return;
    int l  = tid & 63;
    int kt = (tid >> 6) % 80;
    int gt = tid / (80 * 64);
    int g = gt * 32 + (l & 31);
    int k = kt * 16 + ((l >> 5) << 3);
    const float* src = (k < HID) ? (W_hh + (size_t)g * HID + k)
                                 : (W_ih + (size_t)g * NX + (k - HID));
    unsigned short* dst = Wpack + ((size_t)(gt * 80 + kt) * 512 + (size_t)l * 8);
    #pragma unroll
    for (int e = 0; e < 8; ++e) dst[e] = f2bf(src[e]);
}

// xm = bf16(x * maskX) — mask values are exactly 0.0 or 2.0, multiply is exact.
__global__ void pack_xm_kernel(const float* __restrict__ x,
                               const float* __restrict__ maskX,
                               unsigned short* __restrict__ xm) {
    size_t tid = (size_t)blockIdx.x * blockDim.x + threadIdx.x; // per 8 elems
    size_t n8 = (size_t)NT * NGRID * NX / 8;
    if (tid >= n8) return;
    size_t base = tid * 8;
    size_t bn = base % ((size_t)NGRID * NX);
    #pragma unroll
    for (int e = 0; e < 8; ++e) xm[base + e] = f2bf(x[base + e] * maskX[bn + e]);
}

// c = 0, h0 = 0, out = b_lin (harness poisons ws/out before every launch)
__global__ void init_state_kernel(float* __restrict__ c_ws,
                                  unsigned short* __restrict__ h0,
                                  float* __restrict__ out,
                                  const float* __restrict__ b_lin) {
    int i = blockIdx.x * blockDim.x + threadIdx.x;
    if (i < NGRID * HID) { c_ws[i] = 0.0f; h0[i] = 0; }
    if (i < NT * NGRID)  { out[i] = b_lin[0]; }
}

// ---------------- per-timestep kernel ----------------
// Grid: 256 WGs of 256 threads. WG tile: 64 b-rows x 32 j.
// Wave w (0..3) computes gate-type w (i,f,g,o) for the whole tile:
//   2 MFMA C-tiles (32x32) over K=1280 = [h_prev (1024) | xm_t (256)].
__global__ __launch_bounds__(256)
void lstm_step_kernel(const unsigned short* __restrict__ h_in,
                      unsigned short* __restrict__ h_out,
                      float* __restrict__ c_ws,
                      const unsigned short* __restrict__ xm,
                      const unsigned short* __restrict__ Wpack,
                      const float* __restrict__ b_ih,
                      const float* __restrict__ b_hh,
                      const float* __restrict__ W_lin,
                      float* __restrict__ out, int t)
{
    __shared__ float lds_g[4 * 64 * 32];  // gate pre-activations [q][b_loc][col]
    __shared__ float h_lds[64 * 32];      // fp32 h for the output projection

    const int tidx = threadIdx.x;
    const int w = tidx >> 6;          // wave id == gate type
    const int l = tidx & 63;
    const int jt = blockIdx.x & 31;   // j-tile (fast-varying -> XCD L2 locality of W)
    const int bi = blockIdx.x >> 5;   // b-tile
    const int b0 = bi * 64;
    const int j0 = jt * 32;

    const int col  = l & 31;
    const int half = l >> 5;
    const int g = w * HID + j0 + col;
    const float bias = b_ih[g] + b_hh[g];

    f32x16 acc0 = {};
    f32x16 acc1 = {};

    const int gt = w * 32 + jt;
    const bf16x8* __restrict__ wv = (const bf16x8*)Wpack + (size_t)gt * 80 * 64 + l;
    const bf16x8* __restrict__ hv = (const bf16x8*)h_in;
    const bf16x8* __restrict__ xv = (const bf16x8*)xm + (size_t)t * NGRID * 32;

    const int rowA0 = b0 + (l & 31);
    const int rowA1 = rowA0 + 32;
    const size_t a0 = (size_t)rowA0 * 128 + half;   // h row in bf16x8 units
    const size_t a1 = (size_t)rowA1 * 128 + half;

    // K = 0..1023 : h_prev @ W_hh^T
    #pragma unroll 4
    for (int kt = 0; kt < 64; ++kt) {
        bf16x8 bfr  = wv[(size_t)kt * 64];
        bf16x8 afr0 = hv[a0 + (size_t)kt * 2];
        bf16x8 afr1 = hv[a1 + (size_t)kt * 2];
        acc0 = __builtin_amdgcn_mfma_f32_32x32x16_bf16(afr0, bfr, acc0, 0, 0, 0);
        acc1 = __builtin_amdgcn_mfma_f32_32x32x16_bf16(afr1, bfr, acc1, 0, 0, 0);
    }
    // K = 1024..1279 : xm_t @ W_ih^T
    const size_t xa0 = (size_t)rowA0 * 32 + half;
    const size_t xa1 = (size_t)rowA1 * 32 + half;
    #pragma unroll 4
    for (int kt = 0; kt < 16; ++kt) {
        bf16x8 bfr  = wv[(size_t)(64 + kt) * 64];
        bf16x8 afr0 = xv[xa0 + (size_t)kt * 2];
        bf16x8 afr1 = xv[xa1 + (size_t)kt * 2];
        acc0 = __builtin_amdgcn_mfma_f32_32x32x16_bf16(afr0, bfr, acc0, 0, 0, 0);
        acc1 = __builtin_amdgcn_mfma_f32_32x32x16_bf16(afr1, bfr, acc1, 0, 0, 0);
    }

    // C/D layout (32x32): col = lane&31, row = (reg&3) + 8*(reg>>2) + 4*(lane>>5)
    #pragma unroll
    for (int r = 0; r < 16; ++r) {
        int row = (r & 3) + 8 * (r >> 2) + 4 * half;
        lds_g[w * 2048 + row * 32 + col]        = acc0[r] + bias;
        lds_g[w * 2048 + (32 + row) * 32 + col] = acc1[r] + bias;
    }
    __syncthreads();

    // cell update (fp32): c = f*c + i*g ; h = o*tanh(c)
    #pragma unroll
    for (int i = 0; i < 8; ++i) {
        int p = tidx + i * 256;          // 0..2047 over [b_loc][col]
        int b_loc = p >> 5, cc = p & 31;
        float ig = sigmoidf_(lds_g[p]);
        float fg = sigmoidf_(lds_g[2048 + p]);
        float gg = tanhf(lds_g[4096 + p]);
        float og = sigmoidf_(lds_g[6144 + p]);
        size_t cidx = (size_t)(b0 + b_loc) * HID + j0 + cc;
        float cn = fg * c_ws[cidx] + ig * gg;
        c_ws[cidx] = cn;
        float h = og * tanhf(cn);
        h_out[cidx] = f2bf(h);
        h_lds[p] = h;
    }
    __syncthreads();

    // out[t,b] += sum_j h[b,j] * W_lin[j]  (over this WG's 32 j)
    {
        int b_loc = tidx >> 2;
        int part = tidx & 3;
        float s = 0.f;
        #pragma unroll
        for (int jj = 0; jj < 8; ++jj) {
            int j = part * 8 + jj;
            s += h_lds[b_loc * 32 + j] * W_lin[j0 + j];
        }
        s += __shfl_xor(s, 1);
        s += __shfl_xor(s, 2);
        if (part == 0) atomicAdd(&out[(size_t)t * NGRID + b0 + b_loc], s);
    }
}

// ---------------- launch ----------------
extern "C" void kernel_launch(void* const* d_in, const int* in_sizes, int n_in,
                              void* d_out, int out_size, void* d_ws, size_t ws_size,
                              hipStream_t stream)
{
    const float* x     = (const float*)d_in[0];
    const float* maskX = (const float*)d_in[1];
    const float* W_ih  = (const float*)d_in[2];
    const float* W_hh  = (const float*)d_in[3];
    const float* b_ih  = (const float*)d_in[4];
    const float* b_hh  = (const float*)d_in[5];
    const float* W_lin = (const float*)d_in[6];
    const float* b_lin = (const float*)d_in[7];
    float* out = (float*)d_out;

    char* ws = (char*)d_ws;
    const size_t WPACK_B = 128ull * 80 * 512 * 2;          // 10,485,760
    const size_t XM_B    = (size_t)NT * NGRID * NX * 2;    // 95,682,560
    const size_t C_B     = (size_t)NGRID * HID * 4;        // 2,097,152
    unsigned short* Wpack = (unsigned short*)ws;
    unsigned short* xm    = (unsigned short*)(ws + WPACK_B);
    float* c_ws           = (float*)(ws + WPACK_B + XM_B);
    unsigned short* hbuf0 = (unsigned short*)(ws + WPACK_B + XM_B + C_B);
    unsigned short* hbuf1 = hbuf0 + (size_t)NGRID * HID;

    init_state_kernel<<<(NGRID * HID + 255) / 256, 256, 0, stream>>>(c_ws, hbuf0, out, b_lin);
    pack_w_kernel<<<(128 * 80 * 64 + 255) / 256, 256, 0, stream>>>(W_ih, W_hh, Wpack);
    size_t nxm = (size_t)NT * NGRID * NX / 8;
    pack_xm_kernel<<<(int)((nxm + 255) / 256), 256, 0, stream>>>(x, maskX, xm);

    const unsigned short* hin = hbuf0;
    unsigned short* hout = hbuf1;
    for (int t = 0; t < NT; ++t) {
        lstm_step_kernel<<<256, 256, 0, stream>>>(hin, hout, c_ws, xm, Wpack,
                                                  b_ih, b_hh, W_lin, out, t);
        unsigned short* tmp = (unsigned short*)hin;
        hin = hout;
        hout = tmp;
    }
}